// Round 2
// baseline (30290.125 us; speedup 1.0000x reference)
//
#include <hip/hip_runtime.h>
#include <hip/hip_bf16.h>

// HierESN (all I/O fp32): out[t] = [v1(t) | v2(t)], v' = .5v + .5tanh(v@W + u@Win)
// Phase A: U = X @ Win1 (bf16 MFMA, fp32 acc)
// Phase B: scan layer1 (sparse bf16-packed W1), writes fp32 out + bf16 V1 history
// Phase C: U = V1bf @ Win2 (reuses U buffer)
// Phase D: scan layer2

typedef __bf16 bf16;
typedef __bf16 bf16x8 __attribute__((ext_vector_type(8)));
typedef float  f32x4  __attribute__((ext_vector_type(4)));

#define RDIM 4000
#define TSTEPS 1000
#define CAP 640   // max nnz/column; binomial(4000,0.1) max ~475

// ---- sparse compression: thread per column j; pack {bf16_bits<<16 | row} ----
__global__ __launch_bounds__(256) void compress_k(const float* __restrict__ W,
                                                  unsigned* __restrict__ packed,
                                                  unsigned* __restrict__ cnt, int n) {
    int j = blockIdx.x * blockDim.x + threadIdx.x;
    if (j >= n) return;
    unsigned c = 0;
    for (int i = 0; i < n; i++) {
        float w = W[(size_t)i * n + j];          // coalesced across lanes
        if (w != 0.0f) {                         // mask zeros are exact fp32 zeros
            unsigned u = __float_as_uint(w);
            unsigned b = (u + 0x7FFFu + ((u >> 16) & 1u)) & 0xFFFF0000u;  // RNE to bf16
            if (c < CAP) packed[(size_t)c * n + j] = b | (unsigned)i;
            c++;
        }
    }
    cnt[j] = (c < CAP) ? c : CAP;
}

// ---- MFMA GEMM: C_f32[M,N] = A[M,K] @ B_f32[K,N], A fp32 or bf16, staged as bf16 ----
#define BM 64
#define BN 64
#define BK 32
#define LDP 56

__device__ inline bf16x8 load8(const float* p) {
    const f32x4* q = (const f32x4*)p;
    f32x4 f0 = q[0], f1 = q[1];
    bf16x8 r;
    r[0] = (bf16)f0[0]; r[1] = (bf16)f0[1]; r[2] = (bf16)f0[2]; r[3] = (bf16)f0[3];
    r[4] = (bf16)f1[0]; r[5] = (bf16)f1[1]; r[6] = (bf16)f1[2]; r[7] = (bf16)f1[3];
    return r;
}
__device__ inline bf16x8 load8(const bf16* p) { return *(const bf16x8*)p; }

template <typename AT>
__global__ __launch_bounds__(256) void gemm_k(const AT* __restrict__ A,
                                              const float* __restrict__ B,
                                              float* __restrict__ C,
                                              int M, int N, int K,
                                              int lda, int ldb, int ldc) {
    __shared__ bf16 As[BM][LDP];   // [m][k]
    __shared__ bf16 Bs[BN][LDP];   // [n][k] (transposed stage)
    int tid  = threadIdx.x;
    int wave = tid >> 6, lane = tid & 63;
    int q    = lane >> 4;          // k-quad
    int l16  = lane & 15;
    int m0 = blockIdx.y * BM;
    int n0 = blockIdx.x * BN;

    int arow = tid >> 2;           // m 0..63
    int acol = (tid & 3) * 8;      // k 0,8,16,24
    int brow = tid >> 3;           // k 0..31
    int bcol = (tid & 7) * 8;      // n 0..56

    f32x4 acc[4];
    for (int nb = 0; nb < 4; nb++) for (int r = 0; r < 4; r++) acc[nb][r] = 0.f;

    for (int k0 = 0; k0 < K; k0 += BK) {
        bf16x8 av; for (int e = 0; e < 8; e++) av[e] = (bf16)0.f;
        if (m0 + arow < M)
            av = load8(A + (size_t)(m0 + arow) * lda + k0 + acol);
        bf16x8 bv;
        if (n0 + bcol + 8 <= N)
            bv = load8(B + (size_t)(k0 + brow) * ldb + n0 + bcol);
        else {
            for (int e = 0; e < 8; e++) {
                int col = n0 + bcol + e;
                bv[e] = (col < N) ? (bf16)B[(size_t)(k0 + brow) * ldb + col] : (bf16)0.f;
            }
        }
        __syncthreads();   // prior tile consumed
        *(bf16x8*)&As[arow][acol] = av;
        for (int e = 0; e < 8; e++) Bs[bcol + e][brow] = bv[e];
        __syncthreads();   // tile ready

        bf16x8 af = *(const bf16x8*)&As[wave * 16 + l16][q * 8];
        #pragma unroll
        for (int nb = 0; nb < 4; nb++) {
            bf16x8 bfr = *(const bf16x8*)&Bs[nb * 16 + l16][q * 8];
            acc[nb] = __builtin_amdgcn_mfma_f32_16x16x32_bf16(af, bfr, acc[nb], 0, 0, 0);
        }
    }

    // C/D: col = lane&15, row = (lane>>4)*4 + r   [m89]
    for (int nb = 0; nb < 4; nb++)
        for (int r = 0; r < 4; r++) {
            int row = m0 + wave * 16 + q * 4 + r;
            int col = n0 + nb * 16 + l16;
            if (row < M && col < N) C[(size_t)row * ldc + col] = acc[nb][r];
        }
}

// ---- one step: z = v@W(sparse) + U[t]; v' = .5v + .5tanh(z) ----
// 125 blocks x 256; block = 32 outputs, 8-way k-split
__global__ __launch_bounds__(256) void step_k(const unsigned* __restrict__ packed,
                                              const unsigned* __restrict__ cnt,
                                              const float* __restrict__ Urow,
                                              const float* __restrict__ vold,
                                              float* __restrict__ vnew,
                                              float* __restrict__ outrow,
                                              bf16* __restrict__ outbf, int n) {
    __shared__ float vsh[RDIM];
    __shared__ float red[256];
    int tid = threadIdx.x;
    for (int i = tid; i < n; i += 256) vsh[i] = vold[i];
    __syncthreads();

    int jl = tid & 31, c = tid >> 5;
    int j = blockIdx.x * 32 + jl;
    unsigned cn = cnt[j];
    float acc = 0.f;
    for (unsigned k = c; k < cn; k += 8) {
        unsigned p = packed[(size_t)k * n + j];               // coalesced
        acc += vsh[p & 0xFFFFu] * __uint_as_float(p & 0xFFFF0000u);
    }
    red[tid] = acc;
    __syncthreads();
    if (tid < 32) {
        float s = 0.f;
        #pragma unroll
        for (int qq = 0; qq < 8; qq++) s += red[qq * 32 + jl];
        float vn = 0.5f * vsh[j] + 0.5f * tanhf(s + Urow[j]);
        vnew[j] = vn;
        outrow[j] = vn;
        if (outbf) outbf[j] = (bf16)vn;
    }
}

// ---- launch ----
extern "C" void kernel_launch(void* const* d_in, const int* in_sizes, int n_in,
                              void* d_out, int out_size, void* d_ws, size_t ws_size,
                              hipStream_t stream) {
    const float* x    = (const float*)d_in[0];   // [1000][4096]
    const float* Win1 = (const float*)d_in[1];   // [4096][4000]
    const float* W1   = (const float*)d_in[2];   // [4000][4000]
    const float* Win2 = (const float*)d_in[3];   // [4000][4000]
    const float* W2   = (const float*)d_in[4];   // [4000][4000]
    float* out = (float*)d_out;                  // [1000][8000] fp32

    char* ws = (char*)d_ws;
    // ws: U 16,000,000 | P1 10,240,000 | P2 10,240,000 | V1bf 8,000,000
    //     | C1 16,000 | C2 16,000 | vbuf 64,000   (~44.6 MB total)
    float*    U    = (float*)(ws);
    unsigned* P1   = (unsigned*)(ws + 16000000);
    unsigned* P2   = (unsigned*)(ws + 26240000);
    bf16*     V1bf = (bf16*)(ws + 36480000);     // [1000][4000] bf16 v1 history
    unsigned* C1   = (unsigned*)(ws + 44480000);
    unsigned* C2   = (unsigned*)(ws + 44496000);
    float*    vbuf = (float*)(ws + 44512000);    // [4][4000] ping-pong states

    hipMemsetAsync(vbuf, 0, 4 * RDIM * sizeof(float), stream);

    compress_k<<<16, 256, 0, stream>>>(W1, P1, C1, RDIM);
    compress_k<<<16, 256, 0, stream>>>(W2, P2, C2, RDIM);

    dim3 gg((RDIM + BN - 1) / BN, (TSTEPS + BM - 1) / BM);   // 63 x 16
    gemm_k<float><<<gg, 256, 0, stream>>>(x, Win1, U, TSTEPS, RDIM, 4096,
                                          4096, RDIM, RDIM);

    for (int t = 0; t < TSTEPS; t++) {
        const float* vo = vbuf + (t & 1) * RDIM;
        float*       vn = vbuf + ((t + 1) & 1) * RDIM;
        step_k<<<125, 256, 0, stream>>>(P1, C1, U + (size_t)t * RDIM, vo, vn,
                                        out + (size_t)t * 8000,
                                        V1bf + (size_t)t * RDIM, RDIM);
    }

    // U2 = V1bf @ Win2 (reuse U; scan1 has consumed it)
    gemm_k<bf16><<<gg, 256, 0, stream>>>(V1bf, Win2, U, TSTEPS, RDIM, RDIM,
                                         RDIM, RDIM, RDIM);

    for (int t = 0; t < TSTEPS; t++) {
        const float* vo = vbuf + 2 * RDIM + (t & 1) * RDIM;
        float*       vn = vbuf + 2 * RDIM + ((t + 1) & 1) * RDIM;
        step_k<<<125, 256, 0, stream>>>(P2, C2, U + (size_t)t * RDIM, vo, vn,
                                        out + (size_t)t * 8000 + RDIM,
                                        nullptr, RDIM);
    }
}